// Round 3
// baseline (179.790 us; speedup 1.0000x reference)
//
#include <hip/hip_runtime.h>
#include <hip/hip_bf16.h>

// B=2, N=2048, E=32768, Fin=256, nhead=8, nhid=8 (C1=64), Fout=64. All f32.
#define BB   2
#define NN   2048
#define FIN  256
#define HH   8
#define NHID 8
#define C1   64
#define FOUT 64
#define MAXD 192   // CSR row cap (Poisson(16) max over 2048 rows ~45)

// ---------------------------------------------------------------------------
// K0: build CSR (WITH duplicate edges) in one workgroup.
// deg count (LDS atomics) -> Hillis-Steele scan (LDS) -> scatter (LDS cursors).
__global__ __launch_bounds__(1024)
void k_graph(const int* __restrict__ edges, int E,
             int* __restrict__ offs, int* __restrict__ csr)
{
    __shared__ int sa[NN], sb[NN], cur[NN];   // 24 KB
    int tid = threadIdx.x;
    for (int i = tid; i < NN; i += 1024) sa[i] = 0;
    __syncthreads();
    for (int e = tid; e < E; e += 1024) atomicAdd(&sa[edges[e]], 1);
    __syncthreads();
    int* s = sa; int* d = sb;
    for (int off = 1; off < NN; off <<= 1) {
        for (int i = tid; i < NN; i += 1024) {
            int v = s[i];
            if (i >= off) v += s[i - off];
            d[i] = v;
        }
        __syncthreads();
        int* t = s; s = d; d = t;
    }
    // s = inclusive scan of deg
    for (int i = tid; i < NN; i += 1024) {
        offs[i + 1] = s[i];
        cur[i] = i ? s[i - 1] : 0;
    }
    if (tid == 0) offs[0] = 0;
    __syncthreads();
    for (int e = tid; e < E; e += 1024) {
        int src = edges[e], t = edges[E + e];
        int pos = atomicAdd(&cur[src], 1);
        csr[pos] = t;
    }
}

// ---------------------------------------------------------------------------
// K1: h1 = x @ W_h (+ fused s1/s2). 16 nodes/block, 4 nodes/wave (4x W reuse).
__global__ __launch_bounds__(256)
void k_gemm1(const float* __restrict__ x, const float* __restrict__ Wh,
             const float* __restrict__ ah,
             float* __restrict__ h1, float* __restrict__ s1h, float* __restrict__ s2h)
{
    __shared__ float xs[16][FIN];   // 16 KB
    int tid = threadIdx.x;
    int base = blockIdx.x * 16;
    const float4* xv = (const float4*)(x + (size_t)base * FIN);
    float4* xsv = (float4*)&xs[0][0];
    #pragma unroll
    for (int i = 0; i < 4; ++i) xsv[tid + 256 * i] = xv[tid + 256 * i];
    __syncthreads();

    int wave = tid >> 6, lane = tid & 63;
    int head = lane >> 3, k = lane & 7;
    const float* Wp = Wh + head * FIN * NHID + k;
    int n0 = wave * 4;
    float acc0 = 0.f, acc1 = 0.f, acc2 = 0.f, acc3 = 0.f;
    #pragma unroll 4
    for (int f = 0; f < FIN; ++f) {
        float w = Wp[f * NHID];
        acc0 += w * xs[n0 + 0][f];
        acc1 += w * xs[n0 + 1][f];
        acc2 += w * xs[n0 + 2][f];
        acc3 += w * xs[n0 + 3][f];
    }
    size_t hb = (size_t)(base + n0) * C1 + lane;
    h1[hb] = acc0; h1[hb + C1] = acc1; h1[hb + 2 * C1] = acc2; h1[hb + 3 * C1] = acc3;

    float a1 = ah[head * 16 + k], a2 = ah[head * 16 + 8 + k];
    float pa0 = acc0 * a1, pa1 = acc1 * a1, pa2 = acc2 * a1, pa3 = acc3 * a1;
    float qa0 = acc0 * a2, qa1 = acc1 * a2, qa2 = acc2 * a2, qa3 = acc3 * a2;
    for (int o = 1; o < 8; o <<= 1) {
        pa0 += __shfl_xor(pa0, o); pa1 += __shfl_xor(pa1, o);
        pa2 += __shfl_xor(pa2, o); pa3 += __shfl_xor(pa3, o);
        qa0 += __shfl_xor(qa0, o); qa1 += __shfl_xor(qa1, o);
        qa2 += __shfl_xor(qa2, o); qa3 += __shfl_xor(qa3, o);
    }
    if (k == 0) {
        float ps[4] = {pa0, pa1, pa2, pa3};
        float qs[4] = {qa0, qa1, qa2, qa3};
        #pragma unroll
        for (int j = 0; j < 4; ++j) {
            int bn = base + n0 + j;
            int b = bn >> 11, n = bn & (NN - 1);
            s1h[(b * HH + head) * NN + n] = ps[j];
            s2h[(b * HH + head) * NN + n] = qs[j];
        }
    }
}

// ---------------------------------------------------------------------------
// K2: layer-1 sparse attention (with local dedup) + elu + gemm2 + s1o/s2o, fused.
// One wave per (b,n); lane = head*8+k for attention, lane = out-channel for gemm2.
__global__ __launch_bounds__(64)
void k_att1g2(const float* __restrict__ h1, const float* __restrict__ s1h,
              const float* __restrict__ s2h, const float* __restrict__ bh,
              const int* __restrict__ offs, const int* __restrict__ csr,
              const float* __restrict__ Wo, const float* __restrict__ ao,
              float* __restrict__ h2, float* __restrict__ s1o, float* __restrict__ s2o)
{
    int bn = blockIdx.x;
    int b = bn >> 11, n = bn & (NN - 1);
    int lane = threadIdx.x;
    __shared__ int tg[MAXD];
    __shared__ unsigned char dupf[MAXD];
    __shared__ float xs[C1];

    int beg = offs[n];
    int d = offs[n + 1] - beg;
    if (d > MAXD) d = MAXD;
    for (int l = lane; l < d; l += 64) tg[l] = csr[beg + l];
    __syncthreads();
    // dedup: flag entries whose target appeared earlier in this row
    for (int l = lane; l < d; l += 64) {
        int t = tg[l], f = 0;
        for (int j = 0; j < l; ++j) f |= (tg[j] == t);
        dupf[l] = (unsigned char)f;
    }
    __syncthreads();

    int head = lane >> 3;
    const float* hp = h1 + (size_t)b * NN * C1 + lane;
    float out;
    if (d == 0) {
        // dense row of -1e20 -> uniform softmax over all N
        float acc = 0.f;
        for (int j = 0; j < NN; ++j) acc += hp[(size_t)j * C1];
        out = acc * (1.0f / NN);
    } else {
        float s1 = s1h[(b * HH + head) * NN + n];
        const float* s2p = s2h + (b * HH + head) * NN;
        float m = -3.4e38f;
        for (int p = 0; p < d; ++p) {
            if (dupf[p]) continue;
            float ee = s1 + s2p[tg[p]];
            ee = ee > 0.f ? ee : 0.2f * ee;
            m = fmaxf(m, ee);
        }
        float den = 0.f, acc = 0.f;
        for (int p = 0; p < d; ++p) {
            if (dupf[p]) continue;
            int t = tg[p];
            float ee = s1 + s2p[t];
            ee = ee > 0.f ? ee : 0.2f * ee;
            float w = expf(ee - m);
            den += w;
            acc += w * hp[(size_t)t * C1];
        }
        out = acc / den;
    }
    out += bh[lane];
    float v = out > 0.f ? out : (expf(out) - 1.f);   // elu
    xs[lane] = v;
    __syncthreads();

    // gemm2: h2[bn][lane] = sum_f xs[f] * Wo[f][lane]
    float acc2 = 0.f;
    #pragma unroll 16
    for (int f = 0; f < C1; ++f) acc2 += xs[f] * Wo[f * FOUT + lane];
    h2[(size_t)bn * FOUT + lane] = acc2;
    float p = acc2 * ao[lane];
    float q = acc2 * ao[FOUT + lane];
    for (int o = 1; o < 64; o <<= 1) { p += __shfl_xor(p, o); q += __shfl_xor(q, o); }
    if (lane == 0) { s1o[bn] = p; s2o[bn] = q; }
}

// ---------------------------------------------------------------------------
// K3: layer-2 sparse attention (with local dedup) -> out2 (pre-logsoftmax).
__global__ __launch_bounds__(64)
void k_att2(const float* __restrict__ h2, const float* __restrict__ s1o,
            const float* __restrict__ s2o, const float* __restrict__ bo,
            const int* __restrict__ offs, const int* __restrict__ csr,
            float* __restrict__ out2)
{
    int bn = blockIdx.x;
    int b = bn >> 11, n = bn & (NN - 1);
    int lane = threadIdx.x;
    __shared__ int tg[MAXD];
    __shared__ unsigned char dupf[MAXD];

    int beg = offs[n];
    int d = offs[n + 1] - beg;
    if (d > MAXD) d = MAXD;
    for (int l = lane; l < d; l += 64) tg[l] = csr[beg + l];
    __syncthreads();
    for (int l = lane; l < d; l += 64) {
        int t = tg[l], f = 0;
        for (int j = 0; j < l; ++j) f |= (tg[j] == t);
        dupf[l] = (unsigned char)f;
    }
    __syncthreads();

    const float* hp = h2 + (size_t)b * NN * FOUT + lane;
    float out;
    if (d == 0) {
        float acc = 0.f;
        for (int j = 0; j < NN; ++j) acc += hp[(size_t)j * FOUT];
        out = acc * (1.0f / NN);
    } else {
        float s1 = s1o[bn];
        const float* s2p = s2o + b * NN;
        float m = -3.4e38f;
        for (int p = 0; p < d; ++p) {
            if (dupf[p]) continue;
            float ee = s1 + s2p[tg[p]];
            ee = ee > 0.f ? ee : 0.2f * ee;
            m = fmaxf(m, ee);
        }
        float den = 0.f, acc = 0.f;
        for (int p = 0; p < d; ++p) {
            if (dupf[p]) continue;
            int t = tg[p];
            float ee = s1 + s2p[t];
            ee = ee > 0.f ? ee : 0.2f * ee;
            float w = expf(ee - m);
            den += w;
            acc += w * hp[(size_t)t * FOUT];
        }
        out = acc / den;
    }
    out2[(size_t)bn * FOUT + lane] = out + bo[lane];
}

// ---------------------------------------------------------------------------
// K4: fused logsumexp over node axis + subtract + store. grid = B*FOUT.
__global__ __launch_bounds__(256)
void k_lsef(const float* __restrict__ out2, float* __restrict__ out)
{
    int b = blockIdx.x >> 6, o = blockIdx.x & 63;
    int tid = threadIdx.x;
    const float* p = out2 + (size_t)b * NN * FOUT + o;
    float v[8];
    float m = -3.4e38f;
    #pragma unroll
    for (int j = 0; j < 8; ++j) {
        v[j] = p[(size_t)(tid + 256 * j) * FOUT];
        m = fmaxf(m, v[j]);
    }
    for (int off = 1; off < 64; off <<= 1) m = fmaxf(m, __shfl_xor(m, off));
    __shared__ float sm[4], ss[4];
    if ((tid & 63) == 0) sm[tid >> 6] = m;
    __syncthreads();
    float M = fmaxf(fmaxf(sm[0], sm[1]), fmaxf(sm[2], sm[3]));
    float sum = 0.f;
    #pragma unroll
    for (int j = 0; j < 8; ++j) sum += expf(v[j] - M);
    for (int off = 1; off < 64; off <<= 1) sum += __shfl_xor(sum, off);
    if ((tid & 63) == 0) ss[tid >> 6] = sum;
    __syncthreads();
    float lse = M + logf(ss[0] + ss[1] + ss[2] + ss[3]);
    float* op = out + (size_t)b * NN * FOUT + o;
    #pragma unroll
    for (int j = 0; j < 8; ++j) op[(size_t)(tid + 256 * j) * FOUT] = v[j] - lse;
}

// ---------------------------------------------------------------------------
extern "C" void kernel_launch(void* const* d_in, const int* in_sizes, int n_in,
                              void* d_out, int out_size, void* d_ws, size_t ws_size,
                              hipStream_t stream)
{
    (void)n_in; (void)out_size; (void)ws_size;
    const float* x     = (const float*)d_in[0];
    const int*   edges = (const int*)d_in[1];
    const float* Wh    = (const float*)d_in[2];
    const float* ah    = (const float*)d_in[3];
    const float* bh    = (const float*)d_in[4];
    const float* Wo    = (const float*)d_in[5];
    const float* ao    = (const float*)d_in[6];
    const float* bo    = (const float*)d_in[7];
    int E = in_sizes[1] / 2;

    char* w = (char*)d_ws;
    float* h1   = (float*)w; w += (size_t)BB * NN * C1 * 4;     // 1 MB
    float* s1h  = (float*)w; w += (size_t)BB * HH * NN * 4;     // 128 KB
    float* s2h  = (float*)w; w += (size_t)BB * HH * NN * 4;     // 128 KB
    float* h2   = (float*)w; w += (size_t)BB * NN * FOUT * 4;   // 1 MB
    float* s1o  = (float*)w; w += (size_t)BB * NN * 4;
    float* s2o  = (float*)w; w += (size_t)BB * NN * 4;
    float* out2 = (float*)w; w += (size_t)BB * NN * FOUT * 4;   // 1 MB
    int*   offs = (int*)w;   w += (size_t)(NN + 1) * 4;
    int*   csr  = (int*)w;   w += (size_t)E * 4;

    k_graph<<<1, 1024, 0, stream>>>(edges, E, offs, csr);
    k_gemm1<<<BB * NN / 16, 256, 0, stream>>>(x, Wh, ah, h1, s1h, s2h);
    k_att1g2<<<BB * NN, 64, 0, stream>>>(h1, s1h, s2h, bh, offs, csr, Wo, ao, h2, s1o, s2o);
    k_att2<<<BB * NN, 64, 0, stream>>>(h2, s1o, s2o, bo, offs, csr, out2);
    k_lsef<<<BB * FOUT, 256, 0, stream>>>(out2, (float*)d_out);
}